// Round 3
// baseline (74.924 us; speedup 1.0000x reference)
//
#include <hip/hip_runtime.h>

// FastHST fused: 4-level 1-D scattering, B=32, T=524288, K=16, PAD=8.
// One kernel; all intermediates in LDS with halo recompute. No d_ws use.
// Output layout selected at runtime from out_size:
//   out_size == B*(h0+h1+h2+h3)      -> real-contiguous (complex64 ref cast to f32 = real part)
//   out_size == 2*B*(h0+h1+h2+h3)    -> interleaved (re,im) float pairs
// Every global store is bounds-guarded against out_size (fault -> wrong-value diagnosis).
//
// Block owns S1=2048 level-1 (x1) positions of one row. x1 halo +-56 covers
// level2 (+-24 at x1) and level3 (x3 +-8 -> x2 +-24 -> x1 +-56).
// All inter-level conv windows land at even local index 2*l (aligned float2 LDS reads).

constexpr int K   = 16;
constexpr int S1  = 2048;
constexpr int H1  = 56;              // x1 halo each side
constexpr int NT1 = S1 + 2 * H1;     // 2160 x1 values per block
constexpr int XT  = 2 * NT1 + 16;    // 4336 input floats staged
constexpr int NT2 = S1 / 2 + 48;     // 1072 x2 values (halo 24)
constexpr int NT3 = S1 / 4 + 16;     // 528  x3 values (halo 8)
constexpr int NTH = 256;

template <int CPLX>
__global__ __launch_bounds__(NTH) void hst_fused_kernel(
    const float* __restrict__ xr, const float* __restrict__ xi,
    const float* __restrict__ psi_r, const float* __restrict__ psi_i,
    const float* __restrict__ phi,
    float* __restrict__ out, long nout,
    long o0, long o1, long o2, long o3,
    int L0, int h0, int h1, int h2, int h3)
{
    __shared__ float sxr[XT];
    __shared__ float sxi[XT];
    __shared__ float sx1[NT1];
    __shared__ float sx2[NT2];
    __shared__ float sx3[NT3];

    const int tid = threadIdx.x;
    const int gx  = blockIdx.x;
    const int b   = blockIdx.y;
    const int s   = gx * S1;                 // first owned x1 index
    const int X0  = 2 * s - 2 * H1 - 8;      // first staged input index (mult of 8)

    const float* rowr = xr + (size_t)b * (size_t)L0;
    const float* rowi = xi + (size_t)b * (size_t)L0;

    float fpr[K], fpi[K], fph[K];
    #pragma unroll
    for (int k = 0; k < K; ++k) { fpr[k] = psi_r[k]; fpi[k] = psi_i[k]; fph[k] = phi[k]; }

    // ---- Phase A: stage input tile ----
    const bool edge = (gx == 0) || (gx == (int)gridDim.x - 1);
    if (!edge) {
        const float4* pr4 = reinterpret_cast<const float4*>(rowr + X0);
        const float4* pi4 = reinterpret_cast<const float4*>(rowi + X0);
        float4* dr4 = reinterpret_cast<float4*>(sxr);
        float4* di4 = reinterpret_cast<float4*>(sxi);
        for (int i = tid; i < XT / 4; i += NTH) {
            dr4[i] = pr4[i];
            di4[i] = pi4[i];
        }
    } else {
        for (int i = tid; i < XT; i += NTH) {
            int g = X0 + i;
            bool ok = (g >= 0) && (g < L0);
            sxr[i] = ok ? rowr[g] : 0.0f;
            sxi[i] = ok ? rowi[g] : 0.0f;
        }
    }
    __syncthreads();

    // ---- Phase B: level 0 -> c0 + sx1 = |psi*x| decimated ----
    for (int lm = tid; lm < NT1; lm += NTH) {
        const float2* wr2 = reinterpret_cast<const float2*>(sxr + 2 * lm);
        const float2* wi2 = reinterpret_cast<const float2*>(sxi + 2 * lm);
        float sr = 0.f, si = 0.f, rr = 0.f, ri = 0.f, ir = 0.f, ii = 0.f;
        #pragma unroll
        for (int k2 = 0; k2 < K / 2; ++k2) {
            float2 a = wr2[k2];
            float2 c = wi2[k2];
            sr = fmaf(fph[2*k2], a.x, sr); sr = fmaf(fph[2*k2+1], a.y, sr);
            if (CPLX) { si = fmaf(fph[2*k2], c.x, si); si = fmaf(fph[2*k2+1], c.y, si); }
            rr = fmaf(fpr[2*k2], a.x, rr); rr = fmaf(fpr[2*k2+1], a.y, rr);
            ri = fmaf(fpi[2*k2], a.x, ri); ri = fmaf(fpi[2*k2+1], a.y, ri);
            ir = fmaf(fpr[2*k2], c.x, ir); ir = fmaf(fpr[2*k2+1], c.y, ir);
            ii = fmaf(fpi[2*k2], c.x, ii); ii = fmaf(fpi[2*k2+1], c.y, ii);
        }
        int m = s - H1 + lm;
        float ur = rr - ii, ui = ri + ir;
        sx1[lm] = (m >= 0 && m < h0) ? sqrtf(fmaf(ur, ur, ui * ui)) : 0.0f;
        if (lm >= H1 && lm < H1 + S1) {
            long e = (long)b * h0 + m;
            if (CPLX) {
                long idx = o0 + 2 * e;
                if (idx + 1 < nout)
                    reinterpret_cast<float2*>(out + idx)[0] = make_float2(sr, si);
            } else {
                long idx = o0 + e;
                if (idx < nout) out[idx] = sr;
            }
        }
    }
    __syncthreads();

    // ---- Phase C: level 1 -> c1 + sx2 ----
    for (int lq = tid; lq < NT2; lq += NTH) {
        const float2* w2 = reinterpret_cast<const float2*>(sx1 + 2 * lq);
        float sp = 0.f, ur = 0.f, ui = 0.f;
        #pragma unroll
        for (int k2 = 0; k2 < K / 2; ++k2) {
            float2 a = w2[k2];
            sp = fmaf(fph[2*k2], a.x, sp); sp = fmaf(fph[2*k2+1], a.y, sp);
            ur = fmaf(fpr[2*k2], a.x, ur); ur = fmaf(fpr[2*k2+1], a.y, ur);
            ui = fmaf(fpi[2*k2], a.x, ui); ui = fmaf(fpi[2*k2+1], a.y, ui);
        }
        int q = s / 2 - 24 + lq;
        sx2[lq] = (q >= 0 && q < h1) ? sqrtf(fmaf(ur, ur, ui * ui)) : 0.0f;
        if (lq >= 24 && lq < 24 + S1 / 2) {
            long e = (long)b * h1 + q;
            if (CPLX) {
                long idx = o1 + 2 * e;
                if (idx + 1 < nout)
                    reinterpret_cast<float2*>(out + idx)[0] = make_float2(sp, 0.0f);
            } else {
                long idx = o1 + e;
                if (idx < nout) out[idx] = sp;
            }
        }
    }
    __syncthreads();

    // ---- Phase D: level 2 -> c2 + sx3 ----
    for (int lp = tid; lp < NT3; lp += NTH) {
        const float2* w2 = reinterpret_cast<const float2*>(sx2 + 2 * lp);
        float sp = 0.f, ur = 0.f, ui = 0.f;
        #pragma unroll
        for (int k2 = 0; k2 < K / 2; ++k2) {
            float2 a = w2[k2];
            sp = fmaf(fph[2*k2], a.x, sp); sp = fmaf(fph[2*k2+1], a.y, sp);
            ur = fmaf(fpr[2*k2], a.x, ur); ur = fmaf(fpr[2*k2+1], a.y, ur);
            ui = fmaf(fpi[2*k2], a.x, ui); ui = fmaf(fpi[2*k2+1], a.y, ui);
        }
        int p = s / 4 - 8 + lp;
        sx3[lp] = (p >= 0 && p < h2) ? sqrtf(fmaf(ur, ur, ui * ui)) : 0.0f;
        if (lp >= 8 && lp < 8 + S1 / 4) {
            long e = (long)b * h2 + p;
            if (CPLX) {
                long idx = o2 + 2 * e;
                if (idx + 1 < nout)
                    reinterpret_cast<float2*>(out + idx)[0] = make_float2(sp, 0.0f);
            } else {
                long idx = o2 + e;
                if (idx < nout) out[idx] = sp;
            }
        }
    }
    __syncthreads();

    // ---- Phase E: level 3 -> c3 (phi conv only; x4 unused by reference) ----
    {
        const int v = s / 8 + tid;               // S1/8 == 256 == blockDim
        const float2* w2 = reinterpret_cast<const float2*>(sx3 + 2 * tid);
        float sp = 0.f;
        #pragma unroll
        for (int k2 = 0; k2 < K / 2; ++k2) {
            float2 a = w2[k2];
            sp = fmaf(fph[2*k2], a.x, sp); sp = fmaf(fph[2*k2+1], a.y, sp);
        }
        long e = (long)b * h3 + v;
        if (CPLX) {
            long idx = o3 + 2 * e;
            if (idx + 1 < nout)
                reinterpret_cast<float2*>(out + idx)[0] = make_float2(sp, 0.0f);
        } else {
            long idx = o3 + e;
            if (idx < nout) out[idx] = sp;
        }
    }
}

extern "C" void kernel_launch(void* const* d_in, const int* in_sizes, int n_in,
                              void* d_out, int out_size, void* d_ws, size_t ws_size,
                              hipStream_t stream) {
    const float* xr    = (const float*)d_in[0];
    const float* xi    = (const float*)d_in[1];
    const float* psi_r = (const float*)d_in[2];
    const float* psi_i = (const float*)d_in[3];
    const float* phi   = (const float*)d_in[4];
    float* out = (float*)d_out;

    const int B  = 32;
    const int T  = in_sizes[0] / B;      // 524288
    const int L0 = T;
    const int h0 = L0 / 2;               // 262144
    const int h1 = h0 / 2;               // 131072
    const int h2 = h1 / 2;               // 65536
    const int h3 = h2 / 2;               // 32768

    const long realElems = (long)B * ((long)h0 + h1 + h2 + h3);   // 15728640
    const bool cplx = ((long)out_size >= 2 * realElems);

    long o0, o1, o2, o3;
    if (cplx) {
        o0 = 0;
        o1 = o0 + 2l * B * h0;
        o2 = o1 + 2l * B * h1;
        o3 = o2 + 2l * B * h2;
    } else {
        o0 = 0;
        o1 = o0 + (long)B * h0;
        o2 = o1 + (long)B * h1;
        o3 = o2 + (long)B * h2;
    }

    dim3 blk(NTH, 1, 1);
    dim3 grd(h0 / S1, B, 1);             // (128, 32)
    if (cplx) {
        hipLaunchKernelGGL((hst_fused_kernel<1>), grd, blk, 0, stream,
                           xr, xi, psi_r, psi_i, phi,
                           out, (long)out_size, o0, o1, o2, o3,
                           L0, h0, h1, h2, h3);
    } else {
        hipLaunchKernelGGL((hst_fused_kernel<0>), grd, blk, 0, stream,
                           xr, xi, psi_r, psi_i, phi,
                           out, (long)out_size, o0, o1, o2, o3,
                           L0, h0, h1, h2, h3);
    }
}